// Round 8
// baseline (171.104 us; speedup 1.0000x reference)
//
#include <hip/hip_runtime.h>
#include <math.h>
#include <stdint.h>

#define V 128
#define M 256
#define CAT 64
#define B 256
#define LAYERS 4
#define K 4
#define AR 2
#define NNODES 32768
#define E (NNODES * K)
#define NUM_INPUT (V * M)
#define BASE (1 + NUM_INPUT)
#define TOTAL_ROWS (BASE + LAYERS * NNODES)   // 163841
#define L3N 32
#define NPART (NNODES / L3N)   // 1024
#define R1BLK 32

typedef _Float16 half8 __attribute__((ext_vector_type(8)));
typedef float float8_t __attribute__((ext_vector_type(8)));

// Per-layer storage offsets: stored = true_value + OFF (keeps fp16 small).
#define OFF_IN 5.2f
__device__ __forceinline__ float layer_off(int l) {
    return (l == 0) ? 11.4f : (l == 1) ? 23.5f : (l == 2) ? 47.5f : 95.5f;
}
__device__ __forceinline__ float row_off(int row) {
    if (row < BASE) return OFF_IN;
    return layer_off((row - BASE) >> 15);
}

// ============ Kernel A: input prep ============
// Normalizes input logits into logp16[NUM_INPUT][64] fp16 (+OFF_IN baked in)
// and transposes categories into cats_u8[V][B]. in_mars is NEVER materialized.
__global__ __launch_bounds__(256) void input_prep_kernel(
    const int* __restrict__ inputs,          // [B, V] int32
    const float* __restrict__ input_logits,  // [NUM_INPUT, CAT]
    _Float16* __restrict__ logp16,           // [NUM_INPUT, 64]
    unsigned char* __restrict__ cats)        // [V, B]
{
    const int t = threadIdx.x;
    const int n0 = blockIdx.x * 4;
    const int w = t >> 6;      // node within block (one per wave)
    const int l = t & 63;      // category
    const int n = n0 + w;

    const float x = input_logits[(size_t)n * CAT + l];
    float m = x;
    #pragma unroll
    for (int off = 32; off >= 1; off >>= 1) m = fmaxf(m, __shfl_xor(m, off));
    float s = __expf(x - m);
    #pragma unroll
    for (int off = 32; off >= 1; off >>= 1) s += __shfl_xor(s, off);
    const float logZ = m + __logf(s);

    logp16[(size_t)n * 64 + l] = (_Float16)(x - logZ + OFF_IN);

    if ((blockIdx.x & 63) == 0) {            // first block of each variable
        const int v = blockIdx.x >> 6;
        cats[(size_t)v * B + t] = (unsigned char)inputs[t * V + v];
    }
}

// ---- shared child-row machinery (two-pass: stage loads, then finish) ----
// stage: issue the memory ops for child row r into 4 u32 regs.
//   r >= BASE : full 16-B row slice from buf.
//   r <  BASE : compressed input row: u32 of 2 fp16 cats (s0) + u64 cat bytes.
// finish: reconstruct 8 f32 batch values (bpermute selection for compressed).
#define STAGE_CHILD(r, lane, bufq, lpu, catsu, S0, S1, S2, S3)                \
    if ((r) >= BASE) {                                                        \
        const uint4 q = (bufq)[(size_t)(r) * 32 + (lane)];                    \
        S0 = q.x; S1 = q.y; S2 = q.z; S3 = q.w;                               \
    } else {                                                                  \
        const int nn_ = (r) - 1;                                              \
        S0 = (lpu)[(size_t)nn_ * 32 + (lane)];                                \
        const uint64_t cc_ = (catsu)[(size_t)(nn_ >> 8) * 32 + (lane)];       \
        S1 = (uint32_t)cc_; S2 = (uint32_t)(cc_ >> 32); S3 = 0u;              \
    }

__device__ __forceinline__ float8_t finish_child(
    int r, int phys, uint32_t s0, uint32_t s1, uint32_t s2, uint32_t s3)
{
    float8_t val;
    if (r >= BASE) {
        union { uint32_t u[4]; half8 hh; } q;
        q.u[0] = s0; q.u[1] = s1; q.u[2] = s2; q.u[3] = s3;
        val = __builtin_convertvector(q.hh, float8_t);
    } else {
        const uint32_t bl = (uint32_t)(phys & 32);
        #pragma unroll
        for (int j = 0; j < 8; ++j) {
            const uint32_t cb = (((j < 4) ? s1 : s2) >> (8 * (j & 3))) & 63u;
            const uint32_t got = (uint32_t)__builtin_amdgcn_ds_bpermute(
                (int)(((cb >> 1) | bl) << 2), (int)s0);
            const unsigned short hb = (cb & 1u) ? (unsigned short)(got >> 16)
                                                : (unsigned short)(got & 0xffffu);
            union { unsigned short u; _Float16 h; } cv; cv.u = hb;
            val[j] = (float)cv.h;
        }
    }
    return val;
}

// ============ Kernel B: gather layer (8 nodes/block) ============
__global__ __launch_bounds__(256) void layer_kernel(
    const int* __restrict__ child,   // [E, AR] for this layer
    const float* __restrict__ slog,  // [N, K]
    const _Float16* __restrict__ logp16,
    const unsigned char* __restrict__ cats,
    _Float16* __restrict__ buf,
    int out_row0, int layer)
{
    __shared__ int ch[8][K * AR];
    __shared__ float w[8][K];
    const int t = threadIdx.x;
    const int i0 = blockIdx.x * 8;

    if (t < 64) ((int*)ch)[t] = child[(size_t)i0 * (K * AR) + t];
    __syncthreads();

    if (t < 32) {
        const float x = slog[(size_t)i0 * K + t];
        float mm = fmaxf(x, __shfl_xor(x, 1));
        mm = fmaxf(mm, __shfl_xor(mm, 2));
        float e = __expf(x - mm);
        float ss = e + __shfl_xor(e, 1);
        ss += __shfl_xor(ss, 2);
        const float lz = mm + __logf(ss);
        const int j = t >> 2, k = t & 3;
        w[j][k] = x - lz - row_off(ch[j][2 * k]) - row_off(ch[j][2 * k + 1])
                  + layer_off(layer);
    }
    __syncthreads();

    const int g = t >> 5, lane = t & 31, phys = t & 63;
    const uint4* bufq = (const uint4*)buf;
    const uint32_t* lpu = (const uint32_t*)logp16;
    const uint64_t* catsu = (const uint64_t*)cats;

    // pass 1: issue all 8 child loads (max memory-level parallelism)
    uint32_t s0[8], s1[8], s2[8], s3[8];
    #pragma unroll
    for (int c = 0; c < 8; ++c) {
        const int r = ch[g][c];
        STAGE_CHILD(r, lane, bufq, lpu, catsu, s0[c], s1[c], s2[c], s3[c]);
    }

    // pass 2: reconstruct values, combine
    float8_t v[K];
    #pragma unroll
    for (int k = 0; k < K; ++k) {
        const int c0 = 2 * k, c1 = 2 * k + 1;
        const float8_t a = finish_child(ch[g][c0], phys, s0[c0], s1[c0], s2[c0], s3[c0]);
        const float8_t b = finish_child(ch[g][c1], phys, s0[c1], s1[c1], s2[c1], s3[c1]);
        v[k] = a + b + w[g][k];
    }

    half8 r8;
    #pragma unroll
    for (int j = 0; j < 8; ++j) {
        const float mm = fmaxf(fmaxf(v[0][j], v[1][j]), fmaxf(v[2][j], v[3][j]));
        const float ss = __expf(v[0][j] - mm) + __expf(v[1][j] - mm) +
                         __expf(v[2][j] - mm) + __expf(v[3][j] - mm);
        r8[j] = (_Float16)(mm + __logf(ss));
    }
    ((half8*)buf)[(size_t)(out_row0 + i0 + g) * 32 + lane] = r8;
}

// ============ Kernel B3: fused layer 3 + root partial (1024 blocks) ========
__global__ __launch_bounds__(1024) void layer3_root_kernel(
    const int* __restrict__ child,   // layer-3 [E, AR]
    const float* __restrict__ slog,  // layer-3 [N, K]
    const _Float16* __restrict__ logp16,
    const unsigned char* __restrict__ cats,
    const _Float16* __restrict__ buf,
    const float* __restrict__ rlog,  // [N]
    float* __restrict__ pm, float* __restrict__ ps)  // [NPART, B]
{
    __shared__ int ch[L3N][K * AR];
    __shared__ float w[L3N][K];
    __shared__ float rl[L3N];
    __shared__ float vmat[B][L3N + 1];
    const int t = threadIdx.x;
    const int i0 = blockIdx.x * L3N;
    const float off3 = layer_off(3);

    if (t < L3N * 8) ((int*)ch)[t] = child[(size_t)i0 * (K * AR) + t];
    if (t >= 512 && t < 512 + L3N) rl[t - 512] = rlog[i0 + (t - 512)];
    __syncthreads();

    if (t < L3N * 4) {
        const float x = slog[(size_t)i0 * K + t];
        float mm = fmaxf(x, __shfl_xor(x, 1));
        mm = fmaxf(mm, __shfl_xor(mm, 2));
        float e = __expf(x - mm);
        float ss = e + __shfl_xor(e, 1);
        ss += __shfl_xor(ss, 2);
        const float lz = mm + __logf(ss);
        const int j = t >> 2, k = t & 3;
        w[j][k] = x - lz - row_off(ch[j][2 * k]) - row_off(ch[j][2 * k + 1])
                  + off3;
    }
    __syncthreads();

    const int g = t >> 5, lane = t & 31, phys = t & 63;
    const uint4* bufq = (const uint4*)buf;
    const uint32_t* lpu = (const uint32_t*)logp16;
    const uint64_t* catsu = (const uint64_t*)cats;

    uint32_t s0[8], s1[8], s2[8], s3[8];
    #pragma unroll
    for (int c = 0; c < 8; ++c) {
        const int r = ch[g][c];
        STAGE_CHILD(r, lane, bufq, lpu, catsu, s0[c], s1[c], s2[c], s3[c]);
    }

    float8_t v[K];
    #pragma unroll
    for (int k = 0; k < K; ++k) {
        const int c0 = 2 * k, c1 = 2 * k + 1;
        const float8_t a = finish_child(ch[g][c0], phys, s0[c0], s1[c0], s2[c0], s3[c0]);
        const float8_t b = finish_child(ch[g][c1], phys, s0[c1], s1[c1], s2[c1], s3[c1]);
        v[k] = a + b + w[g][k];
    }

    const float radd = rl[g] - off3;
    #pragma unroll
    for (int j = 0; j < 8; ++j) {
        const float mm = fmaxf(fmaxf(v[0][j], v[1][j]), fmaxf(v[2][j], v[3][j]));
        const float ss = __expf(v[0][j] - mm) + __expf(v[1][j] - mm) +
                         __expf(v[2][j] - mm) + __expf(v[3][j] - mm);
        vmat[8 * lane + j][g] = mm + __logf(ss) + radd;
    }
    __syncthreads();

    if (t < B) {
        float m = -INFINITY;
        #pragma unroll
        for (int q = 0; q < L3N; ++q) m = fmaxf(m, vmat[t][q]);
        float s = 0.0f;
        #pragma unroll
        for (int q = 0; q < L3N; ++q) s += __expf(vmat[t][q] - m);
        pm[blockIdx.x * B + t] = m;
        ps[blockIdx.x * B + t] = s;
    }
}

// ============ Kernel C: partial tree reduce 1024 -> 32 ============
__global__ __launch_bounds__(256) void root_reduce1(
    const float* __restrict__ pm, const float* __restrict__ ps,
    float* __restrict__ pm2, float* __restrict__ ps2)
{
    const int j = blockIdx.x;
    const int c = threadIdx.x;
    const int Q = NPART / R1BLK;     // 32
    const int p0 = j * Q;

    float m = -INFINITY;
    #pragma unroll 8
    for (int q = 0; q < Q; ++q) m = fmaxf(m, pm[(p0 + q) * B + c]);
    float s = 0.0f;
    #pragma unroll 8
    for (int q = 0; q < Q; ++q)
        s += ps[(p0 + q) * B + c] * __expf(pm[(p0 + q) * B + c] - m);
    pm2[j * B + c] = m;
    ps2[j * B + c] = s;
}

// ============ Kernel D: combine + root normalizer ============
__global__ __launch_bounds__(256) void root_combine_kernel(
    const float* __restrict__ rlog,
    const float* __restrict__ pm2, const float* __restrict__ ps2,
    float* __restrict__ out)
{
    __shared__ float red[256];
    const int t = threadIdx.x;

    float a0 = -INFINITY, a1 = -INFINITY, a2 = -INFINITY, a3 = -INFINITY;
    #pragma unroll 4
    for (int n = t; n < NNODES; n += 1024) {
        a0 = fmaxf(a0, rlog[n]);
        a1 = fmaxf(a1, rlog[n + 256]);
        a2 = fmaxf(a2, rlog[n + 512]);
        a3 = fmaxf(a3, rlog[n + 768]);
    }
    red[t] = fmaxf(fmaxf(a0, a1), fmaxf(a2, a3));
    __syncthreads();
    for (int off = 128; off >= 1; off >>= 1) {
        if (t < off) red[t] = fmaxf(red[t], red[t + off]);
        __syncthreads();
    }
    const float gm = red[0];
    __syncthreads();

    float b0 = 0.f, b1 = 0.f, b2 = 0.f, b3 = 0.f;
    #pragma unroll 4
    for (int n = t; n < NNODES; n += 1024) {
        b0 += __expf(rlog[n]       - gm);
        b1 += __expf(rlog[n + 256] - gm);
        b2 += __expf(rlog[n + 512] - gm);
        b3 += __expf(rlog[n + 768] - gm);
    }
    red[t] = (b0 + b1) + (b2 + b3);
    __syncthreads();
    for (int off = 128; off >= 1; off >>= 1) {
        if (t < off) red[t] += red[t + off];
        __syncthreads();
    }
    const float logZ = gm + __logf(red[0]);

    float m = -INFINITY;
    #pragma unroll 8
    for (int p = 0; p < R1BLK; ++p) m = fmaxf(m, pm2[p * B + t]);
    float s = 0.0f;
    #pragma unroll 8
    for (int p = 0; p < R1BLK; ++p)
        s += ps2[p * B + t] * __expf(pm2[p * B + t] - m);
    out[t] = m + __logf(s) - logZ;
}

// ========================== Launcher ==========================
extern "C" void kernel_launch(void* const* d_in, const int* in_sizes, int n_in,
                              void* d_out, int out_size, void* d_ws, size_t ws_size,
                              hipStream_t stream) {
    const int*   inputs       = (const int*)d_in[0];    // [B, V]
    const float* input_logits = (const float*)d_in[1];  // [NUM_INPUT, CAT]
    const float* sum_logits   = (const float*)d_in[2];  // [LAYERS, N, K]
    const float* root_logits  = (const float*)d_in[3];  // [N]
    const int*   child        = (const int*)d_in[4];    // [LAYERS, E, AR]
    float* out = (float*)d_out;                          // [B, 1]

    _Float16* buf = (_Float16*)d_ws;                     // [TOTAL_ROWS, B] fp16 (rows < BASE unused)
    _Float16* logp16 = buf + (size_t)TOTAL_ROWS * B;     // [NUM_INPUT, 64]
    unsigned char* cats = (unsigned char*)(logp16 + (size_t)NUM_INPUT * 64);  // [V, B]
    float* pm  = (float*)(cats + (size_t)V * B);         // [NPART, B]
    float* ps  = pm  + (size_t)NPART * B;                // [NPART, B]
    float* pm2 = ps  + (size_t)NPART * B;                // [R1BLK, B]
    float* ps2 = pm2 + (size_t)R1BLK * B;                // [R1BLK, B]

    input_prep_kernel<<<NUM_INPUT / 4, 256, 0, stream>>>(inputs, input_logits,
                                                         logp16, cats);

    for (int l = 0; l < LAYERS - 1; ++l) {
        layer_kernel<<<NNODES / 8, 256, 0, stream>>>(
            child + (size_t)l * E * AR,
            sum_logits + (size_t)l * NNODES * K,
            logp16, cats, buf, BASE + l * NNODES, l);
    }

    layer3_root_kernel<<<NPART, 1024, 0, stream>>>(
        child + (size_t)(LAYERS - 1) * E * AR,
        sum_logits + (size_t)(LAYERS - 1) * NNODES * K,
        logp16, cats, buf, root_logits, pm, ps);

    root_reduce1<<<R1BLK, 256, 0, stream>>>(pm, ps, pm2, ps2);
    root_combine_kernel<<<1, 256, 0, stream>>>(root_logits, pm2, ps2, out);
}

// Round 9
// 163.158 us; speedup vs baseline: 1.0487x; 1.0487x over previous
//
#include <hip/hip_runtime.h>
#include <math.h>
#include <stdint.h>

#define V 128
#define M 256
#define CAT 64
#define B 256
#define LAYERS 4
#define K 4
#define AR 2
#define NNODES 32768
#define E (NNODES * K)
#define NUM_INPUT (V * M)
#define BASE (1 + NUM_INPUT)
#define TOTAL_ROWS (BASE + LAYERS * NNODES)   // 163841
#define NPART 1024             // layer-3 chunks (32 nodes each)
#define R1BLK 32

typedef _Float16 half4 __attribute__((ext_vector_type(4)));
typedef float float4v __attribute__((ext_vector_type(4)));

// Per-layer storage offsets: stored = true_value + OFF (keeps fp16 small).
#define OFF_IN 5.2f
__device__ __forceinline__ float layer_off(int l) {
    return (l == 0) ? 11.4f : (l == 1) ? 23.5f : (l == 2) ? 47.5f : 95.5f;
}
__device__ __forceinline__ float row_off(int row) {
    if (row < BASE) return OFF_IN;
    return layer_off((row - BASE) >> 15);
}

// ============ Kernel A: input layer (R4-proven; writes full rows) ==========
__global__ __launch_bounds__(256) void input_layer_kernel(
    const int* __restrict__ inputs,          // [B, V] int32
    const float* __restrict__ input_logits,  // [NUM_INPUT, CAT]
    _Float16* __restrict__ buf)              // [TOTAL_ROWS, B] fp16 (+offsets)
{
    __shared__ float lg[4][CAT];
    __shared__ int cats[B];
    __shared__ float lzs[4];
    const int t = threadIdx.x;
    const int n0 = blockIdx.x * 4;

    lg[t >> 6][t & 63] = input_logits[(size_t)n0 * CAT + t];
    cats[t] = inputs[t * V + (n0 >> 8)];     // vid = n0/M, same for 4 nodes
    __syncthreads();

    const int w = t >> 6;   // wave = node within group
    const int l = t & 63;   // lane
    float x = lg[w][l];
    float m = x;
    #pragma unroll
    for (int off = 32; off >= 1; off >>= 1) m = fmaxf(m, __shfl_xor(m, off));
    float s = __expf(x - m);
    #pragma unroll
    for (int off = 32; off >= 1; off >>= 1) s += __shfl_xor(s, off);
    if (l == 0) lzs[w] = m + __logf(s);
    __syncthreads();

    const float logZ = lzs[w];
    half4 r;
    #pragma unroll
    for (int j = 0; j < 4; ++j) {
        const int c = cats[4 * l + j];
        r[j] = (_Float16)(lg[w][c] - logZ + OFF_IN);
    }
    ((half4*)buf)[(size_t)(1 + n0 + w) * (B / 4) + l] = r;

    if (blockIdx.x == 0 && t < B / 4) {      // dummy node row 0
        half4 z;
        z[0] = z[1] = z[2] = z[3] = (_Float16)OFF_IN;
        ((half4*)buf)[t] = z;
    }
}

// ============ Kernel B: XCD-sliced gather layer ============
// Block b: xcd = b&7 (round-robin dispatch heuristic), chunk = b>>3.
// Processes 32 nodes x cols [xcd*32, xcd*32+32) — 64 B per row read, so the
// per-(layer,XCD) gather working set (2-8 MB) is L2-resident.
__global__ __launch_bounds__(256) void layer_kernel_xcd(
    const int* __restrict__ child,   // [E, AR] for this layer
    const float* __restrict__ slog,  // [N, K]
    _Float16* __restrict__ buf,      // [TOTAL_ROWS, B]
    int out_row0, int layer)
{
    __shared__ int ch[32][K * AR];
    __shared__ float w[32][K];
    const int t = threadIdx.x;
    const int xcd = blockIdx.x & 7;
    const int chunk = blockIdx.x >> 3;
    const int i0 = chunk * 32;

    ((int*)ch)[t] = child[(size_t)i0 * (K * AR) + t];   // 256 ints exactly
    __syncthreads();

    if (t < 128) {   // 32 nodes x 4 logits; 4-lane-group LSE
        const float x = slog[(size_t)i0 * K + t];
        float mm = fmaxf(x, __shfl_xor(x, 1));
        mm = fmaxf(mm, __shfl_xor(mm, 2));
        float e = __expf(x - mm);
        float ss = e + __shfl_xor(e, 1);
        ss += __shfl_xor(ss, 2);
        const float lz = mm + __logf(ss);
        const int j = t >> 2, k = t & 3;
        w[j][k] = x - lz - row_off(ch[j][2 * k]) - row_off(ch[j][2 * k + 1])
                  + layer_off(layer);
    }
    __syncthreads();

    const int g = t >> 3;        // node within chunk (0..31)
    const int s = t & 7;         // uint2 (=half4) column within slice
    const int off = xcd * 8 + s; // uint2 offset within row (row = 64 uint2)
    const uint2* bufu = (const uint2*)buf;

    // stage all 8 child-row segments (full memory-level parallelism)
    uint2 st[8];
    #pragma unroll
    for (int c = 0; c < 8; ++c)
        st[c] = bufu[(size_t)ch[g][c] * 64 + off];

    float4v v[K];
    #pragma unroll
    for (int k = 0; k < K; ++k) {
        union { uint2 u; half4 h; } ua, ub;
        ua.u = st[2 * k]; ub.u = st[2 * k + 1];
        v[k] = __builtin_convertvector(ua.h, float4v) +
               __builtin_convertvector(ub.h, float4v) + w[g][k];
    }

    union { uint2 u; half4 h; } ro;
    #pragma unroll
    for (int j = 0; j < 4; ++j) {
        const float mm = fmaxf(fmaxf(v[0][j], v[1][j]), fmaxf(v[2][j], v[3][j]));
        const float ss = __expf(v[0][j] - mm) + __expf(v[1][j] - mm) +
                         __expf(v[2][j] - mm) + __expf(v[3][j] - mm);
        ro.h[j] = (_Float16)(mm + __logf(ss));
    }
    ((uint2*)buf)[(size_t)(out_row0 + i0 + g) * 64 + off] = ro.u;
}

// ============ Kernel B3: XCD-sliced fused layer 3 + root partial ===========
__global__ __launch_bounds__(256) void layer3_root_xcd(
    const int* __restrict__ child,   // layer-3 [E, AR]
    const float* __restrict__ slog,  // layer-3 [N, K]
    const _Float16* __restrict__ buf,
    const float* __restrict__ rlog,  // [N]
    float* __restrict__ pm, float* __restrict__ ps)  // [NPART, B]
{
    __shared__ int ch[32][K * AR];
    __shared__ float w[32][K];
    __shared__ float rl[32];
    __shared__ float vmat[32][33];   // [col-in-slice][node], padded
    const int t = threadIdx.x;
    const int xcd = blockIdx.x & 7;
    const int chunk = blockIdx.x >> 3;
    const int i0 = chunk * 32;
    const float off3 = layer_off(3);

    ((int*)ch)[t] = child[(size_t)i0 * (K * AR) + t];
    __syncthreads();

    if (t < 128) {
        const float x = slog[(size_t)i0 * K + t];
        float mm = fmaxf(x, __shfl_xor(x, 1));
        mm = fmaxf(mm, __shfl_xor(mm, 2));
        float e = __expf(x - mm);
        float ss = e + __shfl_xor(e, 1);
        ss += __shfl_xor(ss, 2);
        const float lz = mm + __logf(ss);
        const int j = t >> 2, k = t & 3;
        w[j][k] = x - lz - row_off(ch[j][2 * k]) - row_off(ch[j][2 * k + 1])
                  + off3;
    } else if (t < 160) {
        rl[t - 128] = rlog[i0 + (t - 128)];
    }
    __syncthreads();

    const int g = t >> 3;
    const int s = t & 7;
    const int off = xcd * 8 + s;
    const uint2* bufu = (const uint2*)buf;

    uint2 st[8];
    #pragma unroll
    for (int c = 0; c < 8; ++c)
        st[c] = bufu[(size_t)ch[g][c] * 64 + off];

    float4v v[K];
    #pragma unroll
    for (int k = 0; k < K; ++k) {
        union { uint2 u; half4 h; } ua, ub;
        ua.u = st[2 * k]; ub.u = st[2 * k + 1];
        v[k] = __builtin_convertvector(ua.h, float4v) +
               __builtin_convertvector(ub.h, float4v) + w[g][k];
    }

    const float radd = rl[g] - off3;   // de-offset + root edge logit
    #pragma unroll
    for (int j = 0; j < 4; ++j) {
        const float mm = fmaxf(fmaxf(v[0][j], v[1][j]), fmaxf(v[2][j], v[3][j]));
        const float ss = __expf(v[0][j] - mm) + __expf(v[1][j] - mm) +
                         __expf(v[2][j] - mm) + __expf(v[3][j] - mm);
        vmat[s * 4 + j][g] = mm + __logf(ss) + radd;
    }
    __syncthreads();

    if (t < 32) {    // per-col LSE over the chunk's 32 nodes
        float m = -INFINITY;
        #pragma unroll
        for (int q = 0; q < 32; ++q) m = fmaxf(m, vmat[t][q]);
        float sum = 0.0f;
        #pragma unroll
        for (int q = 0; q < 32; ++q) sum += __expf(vmat[t][q] - m);
        pm[chunk * B + xcd * 32 + t] = m;
        ps[chunk * B + xcd * 32 + t] = sum;
    }
}

// ============ Kernel C: partial tree reduce 1024 -> 32 (R4-proven) =========
__global__ __launch_bounds__(256) void root_reduce1(
    const float* __restrict__ pm, const float* __restrict__ ps,
    float* __restrict__ pm2, float* __restrict__ ps2)
{
    const int j = blockIdx.x;
    const int c = threadIdx.x;
    const int Q = NPART / R1BLK;     // 32
    const int p0 = j * Q;

    float m = -INFINITY;
    #pragma unroll 8
    for (int q = 0; q < Q; ++q) m = fmaxf(m, pm[(p0 + q) * B + c]);
    float s = 0.0f;
    #pragma unroll 8
    for (int q = 0; q < Q; ++q)
        s += ps[(p0 + q) * B + c] * __expf(pm[(p0 + q) * B + c] - m);
    pm2[j * B + c] = m;
    ps2[j * B + c] = s;
}

// ============ Kernel D: combine + root normalizer (R4-proven) ==============
__global__ __launch_bounds__(256) void root_combine_kernel(
    const float* __restrict__ rlog,
    const float* __restrict__ pm2, const float* __restrict__ ps2,
    float* __restrict__ out)
{
    __shared__ float red[256];
    const int t = threadIdx.x;

    float a0 = -INFINITY, a1 = -INFINITY, a2 = -INFINITY, a3 = -INFINITY;
    #pragma unroll 4
    for (int n = t; n < NNODES; n += 1024) {
        a0 = fmaxf(a0, rlog[n]);
        a1 = fmaxf(a1, rlog[n + 256]);
        a2 = fmaxf(a2, rlog[n + 512]);
        a3 = fmaxf(a3, rlog[n + 768]);
    }
    red[t] = fmaxf(fmaxf(a0, a1), fmaxf(a2, a3));
    __syncthreads();
    for (int off = 128; off >= 1; off >>= 1) {
        if (t < off) red[t] = fmaxf(red[t], red[t + off]);
        __syncthreads();
    }
    const float gm = red[0];
    __syncthreads();

    float b0 = 0.f, b1 = 0.f, b2 = 0.f, b3 = 0.f;
    #pragma unroll 4
    for (int n = t; n < NNODES; n += 1024) {
        b0 += __expf(rlog[n]       - gm);
        b1 += __expf(rlog[n + 256] - gm);
        b2 += __expf(rlog[n + 512] - gm);
        b3 += __expf(rlog[n + 768] - gm);
    }
    red[t] = (b0 + b1) + (b2 + b3);
    __syncthreads();
    for (int off = 128; off >= 1; off >>= 1) {
        if (t < off) red[t] += red[t + off];
        __syncthreads();
    }
    const float logZ = gm + __logf(red[0]);

    float m = -INFINITY;
    #pragma unroll 8
    for (int p = 0; p < R1BLK; ++p) m = fmaxf(m, pm2[p * B + t]);
    float s = 0.0f;
    #pragma unroll 8
    for (int p = 0; p < R1BLK; ++p)
        s += ps2[p * B + t] * __expf(pm2[p * B + t] - m);
    out[t] = m + __logf(s) - logZ;
}

// ========================== Launcher ==========================
extern "C" void kernel_launch(void* const* d_in, const int* in_sizes, int n_in,
                              void* d_out, int out_size, void* d_ws, size_t ws_size,
                              hipStream_t stream) {
    const int*   inputs       = (const int*)d_in[0];    // [B, V]
    const float* input_logits = (const float*)d_in[1];  // [NUM_INPUT, CAT]
    const float* sum_logits   = (const float*)d_in[2];  // [LAYERS, N, K]
    const float* root_logits  = (const float*)d_in[3];  // [N]
    const int*   child        = (const int*)d_in[4];    // [LAYERS, E, AR]
    float* out = (float*)d_out;                          // [B, 1]

    _Float16* buf = (_Float16*)d_ws;                     // [TOTAL_ROWS, B] fp16
    float* pm  = (float*)(buf + (size_t)TOTAL_ROWS * B); // [NPART, B]
    float* ps  = pm  + (size_t)NPART * B;                // [NPART, B]
    float* pm2 = ps  + (size_t)NPART * B;                // [R1BLK, B]
    float* ps2 = pm2 + (size_t)R1BLK * B;                // [R1BLK, B]

    input_layer_kernel<<<NUM_INPUT / 4, 256, 0, stream>>>(inputs, input_logits, buf);

    for (int l = 0; l < LAYERS - 1; ++l) {
        layer_kernel_xcd<<<8 * NPART, 256, 0, stream>>>(
            child + (size_t)l * E * AR,
            sum_logits + (size_t)l * NNODES * K,
            buf, BASE + l * NNODES, l);
    }

    layer3_root_xcd<<<8 * NPART, 256, 0, stream>>>(
        child + (size_t)(LAYERS - 1) * E * AR,
        sum_logits + (size_t)(LAYERS - 1) * NNODES * K,
        buf, root_logits, pm, ps);

    root_reduce1<<<R1BLK, 256, 0, stream>>>(pm, ps, pm2, ps2);
    root_combine_kernel<<<1, 256, 0, stream>>>(root_logits, pm2, ps2, out);
}

// Round 10
// 127.816 us; speedup vs baseline: 1.3387x; 1.2765x over previous
//
#include <hip/hip_runtime.h>
#include <math.h>

#define V 128
#define M 256
#define CAT 64
#define B 256
#define LAYERS 4
#define K 4
#define AR 2
#define N 32768
#define E (N * K)
#define NUM_INPUT (V * M)
#define BASE (1 + NUM_INPUT)
#define TOTAL_ROWS (BASE + LAYERS * N)   // 163841
#define L3N 32                 // nodes per block in fused layer-3 kernel
#define NPART (N / L3N)        // 1024 first-stage partials
#define R1BLK 32               // second-stage partial count

typedef _Float16 half8 __attribute__((ext_vector_type(8)));
typedef _Float16 half4 __attribute__((ext_vector_type(4)));
typedef float float8_t __attribute__((ext_vector_type(8)));

// Per-layer storage offsets: stored = true_value + OFF (keeps fp16 small).
#define OFF_IN 5.2f
__device__ __forceinline__ float layer_off(int l) {
    return (l == 0) ? 11.4f : (l == 1) ? 23.5f : (l == 2) ? 47.5f : 95.5f;
}
__device__ __forceinline__ float row_off(int row) {
    if (row < BASE) return OFF_IN;
    return layer_off((row - BASE) >> 15);
}

// ---------------- Kernel A: input layer (4 nodes/block, fp16 out) ----------
__global__ __launch_bounds__(256) void input_layer_kernel(
    const int* __restrict__ inputs,          // [B, V] int32
    const float* __restrict__ input_logits,  // [NUM_INPUT, CAT]
    _Float16* __restrict__ buf)              // [TOTAL_ROWS, B] fp16 (+offsets)
{
    __shared__ float lg[4][CAT];
    __shared__ int cats[B];
    __shared__ float lzs[4];
    const int t = threadIdx.x;
    const int n0 = blockIdx.x * 4;

    lg[t >> 6][t & 63] = input_logits[(size_t)n0 * CAT + t];
    cats[t] = inputs[t * V + (n0 >> 8)];     // vid = n0/M, same for 4 nodes
    __syncthreads();

    const int w = t >> 6;   // wave = node within group
    const int l = t & 63;   // lane
    float x = lg[w][l];
    float m = x;
    #pragma unroll
    for (int off = 32; off >= 1; off >>= 1) m = fmaxf(m, __shfl_xor(m, off));
    float s = __expf(x - m);
    #pragma unroll
    for (int off = 32; off >= 1; off >>= 1) s += __shfl_xor(s, off);
    if (l == 0) lzs[w] = m + __logf(s);
    __syncthreads();

    const float logZ = lzs[w];
    half4 r;
    #pragma unroll
    for (int j = 0; j < 4; ++j) {
        const int c = cats[4 * l + j];
        r[j] = (_Float16)(lg[w][c] - logZ + OFF_IN);
    }
    ((half4*)buf)[(size_t)(1 + n0 + w) * (B / 4) + l] = r;

    if (blockIdx.x == 0 && t < B / 4) {      // dummy node row 0
        half4 z;
        z[0] = z[1] = z[2] = z[3] = (_Float16)OFF_IN;
        ((half4*)buf)[t] = z;
    }
}

// ---------------- Kernel B: fused prod+sum layer (fp16, 8 nodes/block) -----
__global__ __launch_bounds__(256) void layer_kernel(
    const int* __restrict__ child,   // [E, AR] for this layer (e = i*K + k)
    const float* __restrict__ slog,  // [N, K] for this layer
    _Float16* __restrict__ buf,      // [TOTAL_ROWS, B]
    int out_row0, int layer)
{
    __shared__ int ch[8][K * AR];
    __shared__ float w[8][K];
    const int t = threadIdx.x;
    const int i0 = blockIdx.x * 8;

    if (t < 64) ((int*)ch)[t] = child[(size_t)i0 * (K * AR) + t];
    __syncthreads();

    if (t < 32) {
        const float x = slog[(size_t)i0 * K + t];
        float mm = fmaxf(x, __shfl_xor(x, 1));
        mm = fmaxf(mm, __shfl_xor(mm, 2));
        float e = __expf(x - mm);
        float ss = e + __shfl_xor(e, 1);
        ss += __shfl_xor(ss, 2);
        const float lz = mm + __logf(ss);
        const int j = t >> 2, k = t & 3;
        w[j][k] = x - lz - row_off(ch[j][2 * k]) - row_off(ch[j][2 * k + 1])
                  + layer_off(layer);
    }
    __syncthreads();

    const int g = t >> 5;   // node within the 8-node group
    const int l = t & 31;   // half8 column index
    const half8* bufv = (const half8*)buf;   // row stride = B/8 = 32

    float8_t v[K];
    #pragma unroll
    for (int k = 0; k < K; ++k) {
        const half8 a = bufv[ch[g][2 * k]     * (B / 8) + l];
        const half8 b = bufv[ch[g][2 * k + 1] * (B / 8) + l];
        v[k] = __builtin_convertvector(a, float8_t) +
               __builtin_convertvector(b, float8_t) + w[g][k];
    }

    half8 r;
    #pragma unroll
    for (int j = 0; j < 8; ++j) {
        const float mm = fmaxf(fmaxf(v[0][j], v[1][j]), fmaxf(v[2][j], v[3][j]));
        const float ss = __expf(v[0][j] - mm) + __expf(v[1][j] - mm) +
                         __expf(v[2][j] - mm) + __expf(v[3][j] - mm);
        r[j] = (_Float16)(mm + __logf(ss));
    }
    ((half8*)buf)[(out_row0 + i0 + g) * (B / 8) + l] = r;
}

// ---------------- Kernel B3: fused layer-3 + root partial ------------------
__global__ __launch_bounds__(1024) void layer3_root_kernel(
    const int* __restrict__ child,   // layer-3 [E, AR]
    const float* __restrict__ slog,  // layer-3 [N, K]
    const _Float16* __restrict__ buf,
    const float* __restrict__ rlog,  // [N]
    float* __restrict__ pm, float* __restrict__ ps)  // [NPART, B]
{
    __shared__ int ch[L3N][K * AR];
    __shared__ float w[L3N][K];
    __shared__ float rl[L3N];
    __shared__ float vmat[B][L3N + 1];   // [col][node-in-block], padded
    const int t = threadIdx.x;
    const int i0 = blockIdx.x * L3N;
    const float off3 = layer_off(3);

    if (t < L3N * 8) ((int*)ch)[t] = child[(size_t)i0 * (K * AR) + t];
    if (t >= 512 && t < 512 + L3N) rl[t - 512] = rlog[i0 + (t - 512)];
    __syncthreads();

    if (t < L3N * 4) {   // 128 threads; 4-lane-group LSE of sum logits
        const float x = slog[(size_t)i0 * K + t];
        float mm = fmaxf(x, __shfl_xor(x, 1));
        mm = fmaxf(mm, __shfl_xor(mm, 2));
        float e = __expf(x - mm);
        float ss = e + __shfl_xor(e, 1);
        ss += __shfl_xor(ss, 2);
        const float lz = mm + __logf(ss);
        const int j = t >> 2, k = t & 3;
        w[j][k] = x - lz - row_off(ch[j][2 * k]) - row_off(ch[j][2 * k + 1])
                  + off3;
    }
    __syncthreads();

    const int g = t >> 5;   // node within block (0..31)
    const int l = t & 31;   // half8 column index

    const half8* bufv = (const half8*)buf;
    float8_t v[K];
    #pragma unroll
    for (int k = 0; k < K; ++k) {
        const half8 a = bufv[ch[g][2 * k]     * (B / 8) + l];
        const half8 b = bufv[ch[g][2 * k + 1] * (B / 8) + l];
        v[k] = __builtin_convertvector(a, float8_t) +
               __builtin_convertvector(b, float8_t) + w[g][k];
    }

    const float radd = rl[g] - off3;   // de-offset + root edge logit
    #pragma unroll
    for (int j = 0; j < 8; ++j) {
        const float mm = fmaxf(fmaxf(v[0][j], v[1][j]), fmaxf(v[2][j], v[3][j]));
        const float ss = __expf(v[0][j] - mm) + __expf(v[1][j] - mm) +
                         __expf(v[2][j] - mm) + __expf(v[3][j] - mm);
        vmat[8 * l + j][g] = mm + __logf(ss) + radd;
    }
    __syncthreads();

    if (t < B) {   // per-column LSE over the block's 32 nodes
        float m = -INFINITY;
        #pragma unroll
        for (int q = 0; q < L3N; ++q) m = fmaxf(m, vmat[t][q]);
        float s = 0.0f;
        #pragma unroll
        for (int q = 0; q < L3N; ++q) s += __expf(vmat[t][q] - m);
        pm[blockIdx.x * B + t] = m;
        ps[blockIdx.x * B + t] = s;
    }
}

// ---------------- Kernel C: partial tree reduce 1024 -> 32 -----------------
__global__ __launch_bounds__(256) void root_reduce1(
    const float* __restrict__ pm, const float* __restrict__ ps,
    float* __restrict__ pm2, float* __restrict__ ps2)
{
    const int j = blockIdx.x;        // 0..R1BLK-1
    const int c = threadIdx.x;
    const int Q = NPART / R1BLK;     // 32
    const int p0 = j * Q;

    float m = -INFINITY;
    #pragma unroll 8
    for (int q = 0; q < Q; ++q) m = fmaxf(m, pm[(p0 + q) * B + c]);
    float s = 0.0f;
    #pragma unroll 8
    for (int q = 0; q < Q; ++q)
        s += ps[(p0 + q) * B + c] * __expf(pm[(p0 + q) * B + c] - m);
    pm2[j * B + c] = m;
    ps2[j * B + c] = s;
}

// ---------------- Kernel D: combine + root normalizer ----------------------
__global__ __launch_bounds__(256) void root_combine_kernel(
    const float* __restrict__ rlog,
    const float* __restrict__ pm2, const float* __restrict__ ps2,
    float* __restrict__ out)
{
    __shared__ float red[256];
    const int t = threadIdx.x;

    // logZ of root logits
    float a0 = -INFINITY, a1 = -INFINITY, a2 = -INFINITY, a3 = -INFINITY;
    #pragma unroll 4
    for (int n = t; n < N; n += 1024) {
        a0 = fmaxf(a0, rlog[n]);
        a1 = fmaxf(a1, rlog[n + 256]);
        a2 = fmaxf(a2, rlog[n + 512]);
        a3 = fmaxf(a3, rlog[n + 768]);
    }
    red[t] = fmaxf(fmaxf(a0, a1), fmaxf(a2, a3));
    __syncthreads();
    for (int off = 128; off >= 1; off >>= 1) {
        if (t < off) red[t] = fmaxf(red[t], red[t + off]);
        __syncthreads();
    }
    const float gm = red[0];
    __syncthreads();

    float b0 = 0.f, b1 = 0.f, b2 = 0.f, b3 = 0.f;
    #pragma unroll 4
    for (int n = t; n < N; n += 1024) {
        b0 += __expf(rlog[n]       - gm);
        b1 += __expf(rlog[n + 256] - gm);
        b2 += __expf(rlog[n + 512] - gm);
        b3 += __expf(rlog[n + 768] - gm);
    }
    red[t] = (b0 + b1) + (b2 + b3);
    __syncthreads();
    for (int off = 128; off >= 1; off >>= 1) {
        if (t < off) red[t] += red[t + off];
        __syncthreads();
    }
    const float logZ = gm + __logf(red[0]);

    // combine R1BLK partials for batch column t
    float m = -INFINITY;
    #pragma unroll 8
    for (int p = 0; p < R1BLK; ++p) m = fmaxf(m, pm2[p * B + t]);
    float s = 0.0f;
    #pragma unroll 8
    for (int p = 0; p < R1BLK; ++p)
        s += ps2[p * B + t] * __expf(pm2[p * B + t] - m);
    out[t] = m + __logf(s) - logZ;
}

extern "C" void kernel_launch(void* const* d_in, const int* in_sizes, int n_in,
                              void* d_out, int out_size, void* d_ws, size_t ws_size,
                              hipStream_t stream) {
    const int*   inputs       = (const int*)d_in[0];    // [B, V]
    const float* input_logits = (const float*)d_in[1];  // [NUM_INPUT, CAT]
    const float* sum_logits   = (const float*)d_in[2];  // [LAYERS, N, K]
    const float* root_logits  = (const float*)d_in[3];  // [N]
    const int*   child        = (const int*)d_in[4];    // [LAYERS, E, AR]
    float* out = (float*)d_out;                          // [B, 1]

    _Float16* buf = (_Float16*)d_ws;                     // [TOTAL_ROWS, B] fp16
    float* pm  = (float*)(buf + (size_t)TOTAL_ROWS * B); // [NPART, B]
    float* ps  = pm  + (size_t)NPART * B;                // [NPART, B]
    float* pm2 = ps  + (size_t)NPART * B;                // [R1BLK, B]
    float* ps2 = pm2 + (size_t)R1BLK * B;                // [R1BLK, B]

    input_layer_kernel<<<NUM_INPUT / 4, 256, 0, stream>>>(inputs, input_logits, buf);

    for (int l = 0; l < LAYERS - 1; ++l) {
        layer_kernel<<<N / 8, 256, 0, stream>>>(
            child + (size_t)l * E * AR,
            sum_logits + (size_t)l * N * K,
            buf,
            BASE + l * N, l);
    }

    layer3_root_kernel<<<NPART, 1024, 0, stream>>>(
        child + (size_t)(LAYERS - 1) * E * AR,
        sum_logits + (size_t)(LAYERS - 1) * N * K,
        buf, root_logits, pm, ps);

    root_reduce1<<<R1BLK, 256, 0, stream>>>(pm, ps, pm2, ps2);
    root_combine_kernel<<<1, 256, 0, stream>>>(root_logits, pm2, ps2, out);
}